// Round 1
// 361.399 us; speedup vs baseline: 1.1017x; 1.1017x over previous
//
#include <hip/hip_runtime.h>

// Problem constants
#define NN 50000
#define EE 800000
#define FF 256   // IN = HID = PROJ = 256
#define NBLK 196 // ceil(NN/256)

typedef float    f32x4 __attribute__((ext_vector_type(4)));
typedef _Float16 f16x8 __attribute__((ext_vector_type(8)));
typedef _Float16 f16x4 __attribute__((ext_vector_type(4)));

// ---------------------------------------------------------------------------
// CSR build kernels (unchanged)
// ---------------------------------------------------------------------------

__global__ void count_kernel(const int* __restrict__ ei, int* __restrict__ ec) {
    int e = blockIdx.x * 256 + threadIdx.x;
    if (e < EE) atomicAdd(&ec[ei[EE + e]], 1);
}

__global__ __launch_bounds__(256) void scan_part(const int* __restrict__ ec,
                                                 int* __restrict__ bsum) {
    int i = blockIdx.x * 256 + threadIdx.x;
    int v = (i < NN) ? ec[i] : 0;
#pragma unroll
    for (int d = 1; d < 64; d <<= 1) v += __shfl_xor(v, d);
    __shared__ int wt[4];
    int lane = threadIdx.x & 63, wid = threadIdx.x >> 6;
    if (lane == 0) wt[wid] = v;
    __syncthreads();
    if (threadIdx.x == 0)
        bsum[blockIdx.x] = wt[0] + wt[1] + wt[2] + wt[3];
}

__global__ __launch_bounds__(256) void scan_mid(const int* __restrict__ bsum,
                                                int* __restrict__ boff,
                                                int* __restrict__ rs) {
    const int t = threadIdx.x;
    int v = (t < NBLK) ? bsum[t] : 0;
    int lane = t & 63, wid = t >> 6;
    int x = v;
#pragma unroll
    for (int d = 1; d < 64; d <<= 1) {
        int u = __shfl_up(x, d);
        if (lane >= d) x += u;
    }
    __shared__ int wt[4];
    if (lane == 63) wt[wid] = x;
    __syncthreads();
    int add = 0;
    for (int wi = 0; wi < wid; ++wi) add += wt[wi];
    x += add;                                   // inclusive scan
    if (t < NBLK) boff[t] = x - v;              // exclusive
    if (t == NBLK - 1) rs[NN] = x;              // total == EE
}

__global__ __launch_bounds__(256) void scan_final(const int* __restrict__ ec,
                                                  const int* __restrict__ boff,
                                                  int* __restrict__ rs,
                                                  float* __restrict__ dinv) {
    int i = blockIdx.x * 256 + threadIdx.x;
    int v = (i < NN) ? ec[i] : 0;
    int lane = threadIdx.x & 63, wid = threadIdx.x >> 6;
    int x = v;
#pragma unroll
    for (int d = 1; d < 64; d <<= 1) {
        int u = __shfl_up(x, d);
        if (lane >= d) x += u;
    }
    __shared__ int wt[4];
    if (lane == 63) wt[wid] = x;
    __syncthreads();
    int add = 0;
    for (int wi = 0; wi < wid; ++wi) add += wt[wi];
    x += add;                                   // block-inclusive
    if (i < NN) {
        rs[i]   = x - v + boff[blockIdx.x];     // global exclusive
        dinv[i] = rsqrtf((float)(v + 1));       // deg = edges + self-loop
    }
}

__global__ void fill_kernel(const int* __restrict__ ei, const int* __restrict__ rs,
                            int* __restrict__ cnt, const float* __restrict__ dinv,
                            int2* __restrict__ ecw) {
    int e = blockIdx.x * 256 + threadIdx.x;
    if (e >= EE) return;
    int s = ei[e];
    int d = ei[EE + e];
    int p = rs[d] + atomicAdd(&cnt[d], 1);
    ecw[p] = make_int2(s, __float_as_int(dinv[s]));
}

// ---------------------------------------------------------------------------
// W pack: build the SWIZZLED LDS-image of each B tile chunk so GEMM staging
// is a pure linear global_load_lds copy.
//
// Layout: wp halves, chunk(L, hl, nb, kt) at ((((L*2+hl)*2)+nb)*8 + kt)*4096.
// Within a chunk: 512 granules of 16B. Storage granule p = (rs, cs):
//   original row r = rs ^ ((rs>>2)&1), col-granule c = cs ^ (r&3)
// holding W[kt*32 + c*8 + j][nb*128 + r] as fp16 hi / lo.
// This makes ds_read_b128 of 16 consecutive rows hit all 8 bank slots.
// ---------------------------------------------------------------------------
__global__ void packw_kernel(const float* __restrict__ W1, const float* __restrict__ W2,
                             _Float16* __restrict__ wp) {
    int idx = blockIdx.x * 256 + threadIdx.x;   // 0..16383
    int p   = idx & 511;
    int kt  = (idx >> 9) & 7;
    int nb  = (idx >> 12) & 1;
    int L   = (idx >> 13) & 1;
    const float* W = L ? W2 : W1;
    int rs = p >> 2, cs = p & 3;
    int r  = rs ^ ((rs >> 2) & 1);
    int c  = cs ^ (r & 3);
    int n  = nb * 128 + r;
    int k0 = kt * 32 + c * 8;
    f16x8 hi, lo;
#pragma unroll
    for (int j = 0; j < 8; ++j) {
        float v = W[(size_t)(k0 + j) * 256 + n];
        _Float16 h = (_Float16)v;
        hi[j] = h;
        lo[j] = (_Float16)(v - (float)h);
    }
    size_t ch = ((size_t)((L * 2 + 0) * 2 + nb) * 8 + kt) * 4096;
    size_t cl = ((size_t)((L * 2 + 1) * 2 + nb) * 8 + kt) * 4096;
    *(f16x8*)(wp + ch + (size_t)p * 8) = hi;
    *(f16x8*)(wp + cl + (size_t)p * 8) = lo;
}

// ---------------------------------------------------------------------------
// GEMM: H(fp16)[50000][256] = X @ W via fp16 MFMA, W = Whi + Wlo.
// 512 threads (8 waves: wm 0..1 x wn 0..3), 128x128 tile, BK=32, K=256.
// Double-buffered LDS, staged with global_load_lds width=16 (T3 2-phase):
//   STAGE(kt+1, buf^1); ds_read+MFMA(buf); __syncthreads(); toggle.
// LDS is linear (global_load_lds requirement); bank conflicts avoided by
// XOR-swizzling the *source* addresses (A) / prepacked image (B), with the
// matching XOR applied on the ds_read side.
// ---------------------------------------------------------------------------

__device__ __forceinline__ void gll16(const void* g, void* l) {
    __builtin_amdgcn_global_load_lds(
        (const __attribute__((address_space(1))) void*)g,
        (__attribute__((address_space(3))) void*)l, 16, 0, 0);
}

template<typename AT>
__global__ __launch_bounds__(512) void gemm_kernel(
    const AT* __restrict__ X, const _Float16* __restrict__ Bhi,
    const _Float16* __restrict__ Blo, _Float16* __restrict__ H) {
    __shared__ __align__(16) _Float16 Bh[2][4096];   // 2 x 8KB
    __shared__ __align__(16) _Float16 Bl[2][4096];   // 2 x 8KB
    __shared__ __align__(16) AT       As[2][4096];   // fp32: 2x16KB, fp16: 2x8KB

    const int tid = threadIdx.x;
    const int ln  = tid & 63;
    const int w   = tid >> 6;        // 0..7
    const int wm  = w & 1;           // 2 x 64 rows
    const int wn  = w >> 1;          // 4 x 32 cols
    const int q   = ln >> 4;         // k-group
    const int l16 = ln & 15;
    const int m0  = blockIdx.y * 128;
    const int nb  = blockIdx.x;      // 0/1
    const size_t bchunk = (size_t)nb * 8 * 4096;

    f32x4 acc[4][2] = {};            // [mt][nt]

    // ---- stage tile kt into buffer buf (async, linear LDS dest) ----
    auto stage = [&](int kt, int buf) {
        int g = w * 64 + ln;                       // granule 0..511
        // B hi/lo: prepacked swizzled image -> pure linear copy
        gll16(Bhi + bchunk + (size_t)kt * 4096 + (size_t)g * 8,
              &Bh[buf][w * 512]);
        gll16(Blo + bchunk + (size_t)kt * 4096 + (size_t)g * 8,
              &Bl[buf][w * 512]);
        if constexpr (sizeof(AT) == 4) {
            // fp32 A: 1024 granules (16B = 4 floats), row = 8 granules.
            // storage (rs,cs) <- original (r=rs, c = cs ^ (rs&7))
#pragma unroll
            for (int p = 0; p < 2; ++p) {
                int gg = p * 512 + w * 64 + ln;    // 0..1023
                int rs = gg >> 3, cs = gg & 7;
                int c  = cs ^ (rs & 7);
                int gm = m0 + rs; if (gm > NN - 1) gm = NN - 1;
                gll16((const float*)X + (size_t)gm * FF + kt * 32 + c * 4,
                      (float*)&As[buf][0] + (size_t)(p * 512 + w * 64) * 4);
            }
        } else {
            // fp16 A: 512 granules (16B = 8 halves), row = 4 granules.
            // storage (rs,cs) <- r = rs ^ ((rs>>2)&1), c = cs ^ (r&3)
            int rs = g >> 2, cs = g & 3;
            int r  = rs ^ ((rs >> 2) & 1);
            int c  = cs ^ (r & 3);
            int gm = m0 + r; if (gm > NN - 1) gm = NN - 1;
            gll16((const _Float16*)X + (size_t)gm * FF + kt * 32 + c * 8,
                  (_Float16*)&As[buf][0] + (size_t)(w * 64) * 8);
        }
    };

    // ---- ds_read fragments + MFMA on buffer buf ----
    auto compute = [&](int buf) {
        f16x8 af[4], bhf[2], blf[2];
#pragma unroll
        for (int mt = 0; mt < 4; ++mt) {
            int r = wm * 64 + mt * 16 + l16;
            if constexpr (sizeof(AT) == 4) {
                const float* Ab = (const float*)&As[buf][0];
                f32x4 v0 = *(const f32x4*)(Ab + (size_t)(r * 8 + ((2 * q)     ^ (r & 7))) * 4);
                f32x4 v1 = *(const f32x4*)(Ab + (size_t)(r * 8 + ((2 * q + 1) ^ (r & 7))) * 4);
                f16x8 a;
                a[0] = (_Float16)v0.x; a[1] = (_Float16)v0.y;
                a[2] = (_Float16)v0.z; a[3] = (_Float16)v0.w;
                a[4] = (_Float16)v1.x; a[5] = (_Float16)v1.y;
                a[6] = (_Float16)v1.z; a[7] = (_Float16)v1.w;
                af[mt] = a;
            } else {
                const _Float16* Ab = (const _Float16*)&As[buf][0];
                int rr = r ^ ((r >> 2) & 1);
                af[mt] = *(const f16x8*)(Ab + (size_t)(rr * 4 + (q ^ (r & 3))) * 8);
            }
        }
#pragma unroll
        for (int nt = 0; nt < 2; ++nt) {
            int r  = wn * 32 + nt * 16 + l16;
            int rr = r ^ ((r >> 2) & 1);
            int off = (rr * 4 + (q ^ (r & 3))) * 8;
            bhf[nt] = *(const f16x8*)(&Bh[buf][off]);
            blf[nt] = *(const f16x8*)(&Bl[buf][off]);
        }
#pragma unroll
        for (int mt = 0; mt < 4; ++mt)
#pragma unroll
            for (int nt = 0; nt < 2; ++nt) {
                acc[mt][nt] = __builtin_amdgcn_mfma_f32_16x16x32_f16(af[mt], bhf[nt], acc[mt][nt], 0, 0, 0);
                acc[mt][nt] = __builtin_amdgcn_mfma_f32_16x16x32_f16(af[mt], blf[nt], acc[mt][nt], 0, 0, 0);
            }
    };

    stage(0, 0);
    __syncthreads();                 // drains vmcnt: buf0 ready
    int cur = 0;
#pragma unroll
    for (int kt = 0; kt < 8; ++kt) {
        if (kt < 7) stage(kt + 1, cur ^ 1);   // issue next-tile loads first
        compute(cur);                          // ds_read + 16x2 MFMA
        __syncthreads();                       // drains vmcnt: buf^1 ready
        cur ^= 1;
    }

    // epilogue: C/D layout col = lane&15, row = quad*4 + reg
#pragma unroll
    for (int mt = 0; mt < 4; ++mt)
#pragma unroll
        for (int r4 = 0; r4 < 4; ++r4) {
            int m = m0 + wm * 64 + mt * 16 + q * 4 + r4;
            if (m < NN) {
#pragma unroll
                for (int nt = 0; nt < 2; ++nt) {
                    int n = nb * 128 + wn * 32 + nt * 16 + l16;
                    H[(size_t)m * FF + n] = (_Float16)acc[mt][nt][r4];
                }
            }
        }
}

// ---------------------------------------------------------------------------
// Aggregation + bias + PReLU (unchanged). One wave per row; lane owns 4 feats.
// ---------------------------------------------------------------------------
template<typename OT>
__global__ __launch_bounds__(256) void agg_kernel(
    const _Float16* __restrict__ H, const int* __restrict__ rs,
    const int2* __restrict__ ecw, const float* __restrict__ dinv,
    const float* __restrict__ bias, const float* __restrict__ a_ptr,
    OT* __restrict__ out) {
    const int row  = blockIdx.x * 4 + (threadIdx.x >> 6);
    const int lane = threadIdx.x & 63;
    if (row >= NN) return;

    const float av = a_ptr[0];
    const float di = dinv[row];

    f16x4 hv = *(const f16x4*)(H + (size_t)row * FF + lane * 4);
    float ax = di * (float)hv.x;
    float ay = di * (float)hv.y;
    float az = di * (float)hv.z;
    float aw = di * (float)hv.w;

    int e   = rs[row];
    int end = rs[row + 1];
    for (; e + 3 < end; e += 4) {
        int2 p0 = ecw[e], p1 = ecw[e + 1], p2 = ecw[e + 2], p3 = ecw[e + 3];
        f16x4 h0 = *(const f16x4*)(H + (size_t)p0.x * FF + lane * 4);
        f16x4 h1 = *(const f16x4*)(H + (size_t)p1.x * FF + lane * 4);
        f16x4 h2 = *(const f16x4*)(H + (size_t)p2.x * FF + lane * 4);
        f16x4 h3 = *(const f16x4*)(H + (size_t)p3.x * FF + lane * 4);
        float w0 = __int_as_float(p0.y), w1 = __int_as_float(p1.y);
        float w2 = __int_as_float(p2.y), w3 = __int_as_float(p3.y);
        ax += w0 * (float)h0.x + w1 * (float)h1.x + w2 * (float)h2.x + w3 * (float)h3.x;
        ay += w0 * (float)h0.y + w1 * (float)h1.y + w2 * (float)h2.y + w3 * (float)h3.y;
        az += w0 * (float)h0.z + w1 * (float)h1.z + w2 * (float)h2.z + w3 * (float)h3.z;
        aw += w0 * (float)h0.w + w1 * (float)h1.w + w2 * (float)h2.w + w3 * (float)h3.w;
    }
    for (; e < end; ++e) {
        int2 p = ecw[e];
        float w0 = __int_as_float(p.y);
        f16x4 h0 = *(const f16x4*)(H + (size_t)p.x * FF + lane * 4);
        ax += w0 * (float)h0.x;
        ay += w0 * (float)h0.y;
        az += w0 * (float)h0.z;
        aw += w0 * (float)h0.w;
    }

    f32x4 bv = *(const f32x4*)(bias + lane * 4);
    float r0 = di * ax + bv.x; r0 = (r0 >= 0.f) ? r0 : av * r0;
    float r1 = di * ay + bv.y; r1 = (r1 >= 0.f) ? r1 : av * r1;
    float r2 = di * az + bv.z; r2 = (r2 >= 0.f) ? r2 : av * r2;
    float r3 = di * aw + bv.w; r3 = (r3 >= 0.f) ? r3 : av * r3;
    if constexpr (sizeof(OT) == 4) {
        f32x4 res = {r0, r1, r2, r3};
        *(f32x4*)((float*)out + (size_t)row * FF + lane * 4) = res;
    } else {
        f16x4 res;
        res.x = (_Float16)r0; res.y = (_Float16)r1;
        res.z = (_Float16)r2; res.w = (_Float16)r3;
        *(f16x4*)((_Float16*)out + (size_t)row * FF + lane * 4) = res;
    }
}

// ---------------------------------------------------------------------------
// Launch
// ---------------------------------------------------------------------------
extern "C" void kernel_launch(void* const* d_in, const int* in_sizes, int n_in,
                              void* d_out, int out_size, void* d_ws, size_t ws_size,
                              hipStream_t stream) {
    const float* x  = (const float*)d_in[0];
    const float* W1 = (const float*)d_in[1];
    const float* b1 = (const float*)d_in[2];
    const float* W2 = (const float*)d_in[3];
    const float* b2 = (const float*)d_in[4];
    const float* a  = (const float*)d_in[5];
    const int*   ei = (const int*)d_in[6];
    float* out = (float*)d_out;

    char* ws = (char*)d_ws;
    size_t off = 0;
    auto carve = [&](size_t bytes) -> char* {
        char* p = ws + off;
        off = (off + bytes + 255) & ~(size_t)255;
        return p;
    };
    int*      ec   = (int*)carve((size_t)NN * 4);
    int*      cnt  = (int*)carve((size_t)NN * 4);
    int*      rs   = (int*)carve((size_t)(NN + 1) * 4);
    float*    dinv = (float*)carve((size_t)NN * 4);
    int*      bsum = (int*)carve((size_t)NBLK * 4);
    int*      boff = (int*)carve((size_t)NBLK * 4);
    int2*     ecw  = (int2*)carve((size_t)EE * 8);
    _Float16* wp   = (_Float16*)carve((size_t)4 * 65536 * 2);
    _Float16* h    = (_Float16*)carve((size_t)NN * FF * 2);
    _Float16* h1   = (_Float16*)carve((size_t)NN * FF * 2);

    hipMemsetAsync(ec, 0, (size_t)NN * 4, stream);
    hipMemsetAsync(cnt, 0, (size_t)NN * 4, stream);

    count_kernel<<<(EE + 255) / 256, 256, 0, stream>>>(ei, ec);
    scan_part <<<NBLK, 256, 0, stream>>>(ec, bsum);
    scan_mid  <<<1, 256, 0, stream>>>(bsum, boff, rs);
    scan_final<<<NBLK, 256, 0, stream>>>(ec, boff, rs, dinv);
    fill_kernel<<<(EE + 255) / 256, 256, 0, stream>>>(ei, rs, cnt, dinv, ecw);
    packw_kernel<<<64, 256, 0, stream>>>(W1, W2, wp);

    // layer 1: GEMM (fp32 A) -> agg (fp16 out, feeds GEMM2)
    gemm_kernel<float><<<dim3(2, 391), 512, 0, stream>>>(
        x, wp, wp + 65536, h);
    agg_kernel<_Float16><<<(NN + 3) / 4, 256, 0, stream>>>(h, rs, ecw, dinv, b1, a, h1);
    // layer 2: GEMM (fp16 A) -> agg (fp32 out, final)
    gemm_kernel<_Float16><<<dim3(2, 391), 512, 0, stream>>>(
        h1, wp + 131072, wp + 131072 + 65536, h);
    agg_kernel<float><<<(NN + 3) / 4, 256, 0, stream>>>(h, rs, ecw, dinv, b2, a, out);
}